// Round 1
// baseline (83.569 us; speedup 1.0000x reference)
//
#include <hip/hip_runtime.h>

#define K_CLUST 1024

// Pass 1: per-block LDS presence flags over labels, then one idempotent
// global store per present cluster. No atomics needed (store of 1 races benignly).
__global__ void flags_kernel(const int* __restrict__ labels, int n,
                             int* __restrict__ flags) {
    __shared__ unsigned char lflag[K_CLUST];
    for (int c = threadIdx.x; c < K_CLUST; c += blockDim.x) lflag[c] = 0;
    __syncthreads();

    const int n4 = n >> 2;
    const int4* l4 = (const int4*)labels;
    int idx = blockIdx.x * blockDim.x + threadIdx.x;
    int stride = gridDim.x * blockDim.x;
    for (int i = idx; i < n4; i += stride) {
        int4 v = l4[i];
        lflag[(v.x - 1) & (K_CLUST - 1)] = 1;
        lflag[(v.y - 1) & (K_CLUST - 1)] = 1;
        lflag[(v.z - 1) & (K_CLUST - 1)] = 1;
        lflag[(v.w - 1) & (K_CLUST - 1)] = 1;
    }
    // scalar tail (N is divisible by 4 here, but be safe)
    for (int i = (n4 << 2) + idx; i < n; i += stride)
        lflag[(labels[i] - 1) & (K_CLUST - 1)] = 1;

    __syncthreads();
    for (int c = threadIdx.x; c < K_CLUST; c += blockDim.x)
        if (lflag[c]) flags[c] = 1;
}

// Pass 2: stable double-argsort rank over K=1024 keys, one block of 1024 threads.
// rank[i] = #{j : aa[j] < aa[i]} + #{j < i : aa[j] == aa[i]}; mapping = rank+1.
// Empty clusters get +inf; inf==inf ties break by index (matches stable argsort).
__global__ void rank_kernel(const float* __restrict__ peak,
                            const int* __restrict__ flags,
                            int* __restrict__ mapping) {
    __shared__ float aa[K_CLUST];
    const int t = threadIdx.x;
    aa[t] = flags[t] ? peak[t] : __builtin_huge_valf();
    __syncthreads();
    const float mine = aa[t];
    int rank = 0;
    #pragma unroll 8
    for (int j = 0; j < K_CLUST; ++j) {
        float v = aa[j];
        rank += (v < mine) || (v == mine && j < t);
    }
    mapping[t] = rank + 1;
}

// Pass 3: gather mapping[label-1] for every spike, vectorized int4 in/out.
__global__ void relabel_kernel(const int* __restrict__ labels,
                               const int* __restrict__ mapping,
                               int* __restrict__ out, int n) {
    __shared__ int lmap[K_CLUST];
    for (int c = threadIdx.x; c < K_CLUST; c += blockDim.x) lmap[c] = mapping[c];
    __syncthreads();

    const int n4 = n >> 2;
    const int4* l4 = (const int4*)labels;
    int4* o4 = (int4*)out;
    int idx = blockIdx.x * blockDim.x + threadIdx.x;
    int stride = gridDim.x * blockDim.x;
    for (int i = idx; i < n4; i += stride) {
        int4 v = l4[i];
        int4 r;
        r.x = lmap[(v.x - 1) & (K_CLUST - 1)];
        r.y = lmap[(v.y - 1) & (K_CLUST - 1)];
        r.z = lmap[(v.z - 1) & (K_CLUST - 1)];
        r.w = lmap[(v.w - 1) & (K_CLUST - 1)];
        o4[i] = r;
    }
    for (int i = (n4 << 2) + idx; i < n; i += stride)
        out[i] = lmap[(labels[i] - 1) & (K_CLUST - 1)];
}

extern "C" void kernel_launch(void* const* d_in, const int* in_sizes, int n_in,
                              void* d_out, int out_size, void* d_ws, size_t ws_size,
                              hipStream_t stream) {
    const int*   labels = (const int*)d_in[0];
    const float* peak   = (const float*)d_in[1];
    const int n = in_sizes[0];

    int* flags   = (int*)d_ws;            // K_CLUST ints
    int* mapping = flags + K_CLUST;       // K_CLUST ints

    // d_ws is poisoned 0xAA once and never re-poisoned; flags must start at 0
    // every call. hipMemsetAsync on the stream is graph-capture safe.
    hipMemsetAsync(flags, 0, K_CLUST * sizeof(int), stream);

    const int threads = 256;
    const int blocks  = 2048;  // 256 CUs x 8 blocks, grid-stride covers the rest

    flags_kernel<<<blocks, threads, 0, stream>>>(labels, n, flags);
    rank_kernel<<<1, K_CLUST, 0, stream>>>(peak, flags, mapping);
    relabel_kernel<<<blocks, threads, 0, stream>>>(labels, mapping, (int*)d_out, n);
}

// Round 2
// 47.208 us; speedup vs baseline: 1.7702x; 1.7702x over previous
//
#include <hip/hip_runtime.h>

#define K_CLUST 1024

// Pass 1: per-block LDS presence flags over labels, then one idempotent
// global store per present cluster. No atomics needed (store of 1 races benignly).
__global__ void flags_kernel(const int* __restrict__ labels, int n,
                             int* __restrict__ flags) {
    __shared__ unsigned char lflag[K_CLUST];
    for (int c = threadIdx.x; c < K_CLUST; c += blockDim.x) lflag[c] = 0;
    __syncthreads();

    const int n4 = n >> 2;
    const int4* l4 = (const int4*)labels;
    int idx = blockIdx.x * blockDim.x + threadIdx.x;
    int stride = gridDim.x * blockDim.x;
    for (int i = idx; i < n4; i += stride) {
        int4 v = l4[i];
        lflag[(v.x - 1) & (K_CLUST - 1)] = 1;
        lflag[(v.y - 1) & (K_CLUST - 1)] = 1;
        lflag[(v.z - 1) & (K_CLUST - 1)] = 1;
        lflag[(v.w - 1) & (K_CLUST - 1)] = 1;
    }
    for (int i = (n4 << 2) + idx; i < n; i += stride)
        lflag[(labels[i] - 1) & (K_CLUST - 1)] = 1;

    __syncthreads();
    for (int c = threadIdx.x; c < K_CLUST; c += blockDim.x)
        if (lflag[c]) flags[c] = 1;
}

// Pass 2: stable double-argsort rank. One block PER cluster i (1024 blocks x
// 256 threads) so the O(K^2) compare matrix is fully parallel instead of
// 1024 serial LDS reads per thread on a single CU.
// rank[i] = #{j : aa[j] < aa[i]} + #{j < i : aa[j] == aa[i]}; mapping = rank+1.
// Empty clusters get +inf; inf==inf ties break by index (stable argsort).
__global__ void rank_kernel(const float* __restrict__ peak,
                            const int* __restrict__ flags,
                            int* __restrict__ mapping) {
    __shared__ float aa[K_CLUST];
    __shared__ int partial[4];  // 256 threads = 4 waves
    const int t = threadIdx.x;
    for (int c = t; c < K_CLUST; c += 256)
        aa[c] = flags[c] ? peak[c] : __builtin_huge_valf();
    __syncthreads();

    const int i = blockIdx.x;
    const float mine = aa[i];
    int cnt = 0;
    #pragma unroll
    for (int r = 0; r < K_CLUST / 256; ++r) {
        int j = t + r * 256;
        float v = aa[j];
        cnt += (v < mine) || (v == mine && j < i);
    }
    // wave64 shuffle reduce
    #pragma unroll
    for (int off = 32; off > 0; off >>= 1)
        cnt += __shfl_down(cnt, off, 64);
    if ((t & 63) == 0) partial[t >> 6] = cnt;
    __syncthreads();
    if (t == 0)
        mapping[i] = partial[0] + partial[1] + partial[2] + partial[3] + 1;
}

// Pass 3: gather mapping[label-1] for every spike, vectorized int4 in/out.
__global__ void relabel_kernel(const int* __restrict__ labels,
                               const int* __restrict__ mapping,
                               int* __restrict__ out, int n) {
    __shared__ int lmap[K_CLUST];
    for (int c = threadIdx.x; c < K_CLUST; c += blockDim.x) lmap[c] = mapping[c];
    __syncthreads();

    const int n4 = n >> 2;
    const int4* l4 = (const int4*)labels;
    int4* o4 = (int4*)out;
    int idx = blockIdx.x * blockDim.x + threadIdx.x;
    int stride = gridDim.x * blockDim.x;
    for (int i = idx; i < n4; i += stride) {
        int4 v = l4[i];
        int4 r;
        r.x = lmap[(v.x - 1) & (K_CLUST - 1)];
        r.y = lmap[(v.y - 1) & (K_CLUST - 1)];
        r.z = lmap[(v.z - 1) & (K_CLUST - 1)];
        r.w = lmap[(v.w - 1) & (K_CLUST - 1)];
        o4[i] = r;
    }
    for (int i = (n4 << 2) + idx; i < n; i += stride)
        out[i] = lmap[(labels[i] - 1) & (K_CLUST - 1)];
}

extern "C" void kernel_launch(void* const* d_in, const int* in_sizes, int n_in,
                              void* d_out, int out_size, void* d_ws, size_t ws_size,
                              hipStream_t stream) {
    const int*   labels = (const int*)d_in[0];
    const float* peak   = (const float*)d_in[1];
    const int n = in_sizes[0];

    int* flags   = (int*)d_ws;            // K_CLUST ints
    int* mapping = flags + K_CLUST;       // K_CLUST ints

    // d_ws is poisoned 0xAA once and never re-poisoned; flags must start at 0
    // every call. hipMemsetAsync on the stream is graph-capture safe.
    hipMemsetAsync(flags, 0, K_CLUST * sizeof(int), stream);

    const int threads = 256;
    const int blocks  = 2048;  // 256 CUs x 8 blocks, grid-stride covers the rest

    flags_kernel<<<blocks, threads, 0, stream>>>(labels, n, flags);
    rank_kernel<<<K_CLUST, 256, 0, stream>>>(peak, flags, mapping);
    relabel_kernel<<<blocks, threads, 0, stream>>>(labels, mapping, (int*)d_out, n);
}